// Round 21
// baseline (840.593 us; speedup 1.0000x reference)
//
#include <hip/hip_runtime.h>

// Problem constants (fixed by the reference)
#define NU 100000
#define NV 50000
#define KSUP 5
#define ESUP 400000
#define NEDGE (KSUP * ESUP)   // 2,000,000
#define NE 500000
#define DIN 512
#define DGCN 500
#define FSUP 100     // DGCN / KSUP
#define DSIDE 128
#define HSIDE 64
#define DENC 128
#define NBAS 3
#define NCLS 5

#define TMPW 640     // padded tmp width: 5 supports x 128 (256B-aligned slices)
#define XW 512       // X width: 500 gcn + 12 pad (side lives in sideBuf)
#define KD2 576      // dense2 K: 512 (X) + 64 (sideBuf)

// two-level scatter geometry (node-range = 512 so V-bucket stages in LDS)
#define BNODE 512
#define RU 196       // ceil(NU/512)
#define RV 98        // ceil(NV/512)
#define NBU (KSUP * RU)   // 980 U buckets
#define NBV (KSUP * RV)   // 490 V buckets
#define NBT (NBU + NBV)   // 1470
#define CAPU 2560    // mean 2048, +11 sigma
#define CAPV 5120    // mean 4096, +16 sigma
#define CHUNK 8192   // edges per block in binhist

// grid-partition constants
#define GU128 782    // ceil(NU/128)
#define GV128 391    // ceil(NV/128)
#define GU64 1563    // ceil(NU/64)
#define GV64 782     // ceil(NV/64)
#define GS (GU64 + GV64)           // 2345 side blocks
#define GBIN 245     // ceil(NEDGE/CHUNK)
#define PBS (GBIN + GS)            // side blocks end
#define PB1 (PBS + 1280)           // + wencT2 blocks (640*512/256)
#define PB2 (PB1 + 288)            // + W2u blocks (128*576/256)
#define PB3 (PB2 + 288)            // + W2i blocks
#define PB4 (PB3 + 48)             // + dec cvt blocks (384*128/4/256)
#define PTOT (PB4 + 75000)         // + input cvt blocks ((NU+NV)*512/4/256)

__device__ __forceinline__ ushort f2bf(float x) {
    union { float f; unsigned u; } c; c.f = x;
    unsigned r = (c.u + 0x7FFFu + ((c.u >> 16) & 1u)) >> 16;   // RNE
    return (ushort)r;
}
// unpack a u32 holding two bf16 (lo = even col, hi = odd col)
__device__ __forceinline__ float lof(uint g) { return __uint_as_float(g << 16); }
__device__ __forceinline__ float hif(uint g) { return __uint_as_float(g & 0xffff0000u); }

typedef __attribute__((ext_vector_type(4))) float f32x4;
typedef __attribute__((ext_vector_type(8))) short bf16x8;
typedef __attribute__((address_space(3))) void lds_void;
typedef const __attribute__((address_space(1))) void glob_void;
typedef unsigned long long ull;

// ---------------------------------------------------------------------------
// bf16 MFMA GEMM body: C[M,N](bf16) = A[M,K](bf16,K-major) @ BT[N,K]^T
// 128x128 tile, BK=64, 4 waves (2x2). LDS XOR-swizzled via pre-swizzled
// global source (rule #21). ONE call site per kernel (single __shared__).
__device__ __forceinline__ void gemm_body(
    const ushort* __restrict__ A, const ushort* __restrict__ BT,
    ushort* __restrict__ Cout, int M, int N, int K, int ldc,
    int rowBase, int colBase)
{
    __shared__ ushort As[128 * 64];
    __shared__ ushort Bs[128 * 64];
    const int t = threadIdx.x;
    const int lane = t & 63;
    const int w = t >> 6;
    const int wr = w >> 1, wc = w & 1;

    f32x4 acc[4][4] = {};

    for (int k0 = 0; k0 < K; k0 += 64) {
        #pragma unroll
        for (int i = 0; i < 4; ++i) {
            int chi = i * 256 + t;
            int r = chi >> 3;
            int c = (((chi >> 3) & 7) ^ (chi & 7)) * 8;
            int ga = rowBase + r; if (ga > M - 1) ga = M - 1;
            __builtin_amdgcn_global_load_lds(
                (glob_void*)(A + (size_t)ga * K + k0 + c),
                (lds_void*)(As + (size_t)chi * 8), 16, 0, 0);
            int gb = colBase + r; if (gb > N - 1) gb = N - 1;
            __builtin_amdgcn_global_load_lds(
                (glob_void*)(BT + (size_t)gb * K + k0 + c),
                (lds_void*)(Bs + (size_t)chi * 8), 16, 0, 0);
        }
        __syncthreads();

        #pragma unroll
        for (int kk = 0; kk < 2; ++kk) {
            bf16x8 af[4], bfr[4];
            const int cb2 = (kk * 32 + (lane >> 4) * 8) * 2;
            #pragma unroll
            for (int mi = 0; mi < 4; ++mi) {
                int r = wr * 64 + mi * 16 + (lane & 15);
                int off = (r * 128 + cb2) ^ ((r & 7) << 4);
                af[mi] = *(const bf16x8*)((const char*)As + off);
            }
            #pragma unroll
            for (int nj = 0; nj < 4; ++nj) {
                int r = wc * 64 + nj * 16 + (lane & 15);
                int off = (r * 128 + cb2) ^ ((r & 7) << 4);
                bfr[nj] = *(const bf16x8*)((const char*)Bs + off);
            }
            #pragma unroll
            for (int mi = 0; mi < 4; ++mi)
                #pragma unroll
                for (int nj = 0; nj < 4; ++nj)
                    acc[mi][nj] = __builtin_amdgcn_mfma_f32_16x16x32_bf16(
                        af[mi], bfr[nj], acc[mi][nj], 0, 0, 0);
        }
        __syncthreads();
    }

    #pragma unroll
    for (int mi = 0; mi < 4; ++mi) {
        #pragma unroll
        for (int q = 0; q < 4; ++q) {
            int gr = rowBase + wr * 64 + mi * 16 + (lane >> 4) * 4 + q;
            if (gr >= M) continue;
            #pragma unroll
            for (int nj = 0; nj < 4; ++nj) {
                int gc = colBase + wc * 64 + nj * 16 + (lane & 15);
                Cout[(size_t)gr * ldc + gc] = f2bf(acc[mi][nj][q]);
            }
        }
    }
}

// generic single-matrix bf16 GEMM (used for Vb precompute)
__global__ __launch_bounds__(256) void gemm_bf16_k(
    const ushort* __restrict__ A, const ushort* __restrict__ BT,
    ushort* __restrict__ Cout, int M, int N, int K, int ldc)
{
    gemm_body(A, BT, Cout, M, N, K, ldc, blockIdx.y * 128, blockIdx.x * 128);
}

// fused encoder GEMM: U rows then V rows via blockIdx.y partition
__global__ __launch_bounds__(256) void gemm_enc_k(
    const ushort* __restrict__ u_bf, const ushort* __restrict__ v_bf,
    const ushort* __restrict__ WencT2,
    ushort* __restrict__ tmpU, ushort* __restrict__ tmpV)
{
    int y = blockIdx.y;
    const ushort* A; ushort* C; int M, rowBase;
    if (y < GU128) { A = u_bf; C = tmpU; M = NU; rowBase = y * 128; }
    else           { A = v_bf; C = tmpV; M = NV; rowBase = (y - GU128) * 128; }
    gemm_body(A, WencT2, C, M, TMPW, 512, TMPW, rowBase, blockIdx.x * 128);
}

// fused dense2 GEMM with SPLIT A: k0<512 reads X[M][512]; k0==512 reads
// sideBuf[M][64]. K=576, N=128. W2fT cols remapped to match (see prep_k).
__global__ __launch_bounds__(256) void gemm_d2_k(
    const ushort* __restrict__ Xu, const ushort* __restrict__ Xv,
    const ushort* __restrict__ sideU, const ushort* __restrict__ sideV,
    const ushort* __restrict__ W2u, const ushort* __restrict__ W2i,
    ushort* __restrict__ embU, ushort* __restrict__ embV)
{
    __shared__ ushort As[128 * 64];
    __shared__ ushort Bs[128 * 64];
    int y = blockIdx.y;
    const ushort *X, *S, *BT; ushort* C; int M, rowBase;
    if (y < GU128) { X = Xu; S = sideU; BT = W2u; C = embU; M = NU; rowBase = y * 128; }
    else { X = Xv; S = sideV; BT = W2i; C = embV; M = NV; rowBase = (y - GU128) * 128; }

    const int t = threadIdx.x;
    const int lane = t & 63;
    const int w = t >> 6;
    const int wr = w >> 1, wc = w & 1;

    f32x4 acc[4][4] = {};

    for (int k0 = 0; k0 < KD2; k0 += 64) {
        const bool fromX = (k0 < XW);
        #pragma unroll
        for (int i = 0; i < 4; ++i) {
            int chi = i * 256 + t;
            int r = chi >> 3;
            int c = (((chi >> 3) & 7) ^ (chi & 7)) * 8;
            int ga = rowBase + r; if (ga > M - 1) ga = M - 1;
            const ushort* src = fromX ? (X + (size_t)ga * XW + k0 + c)
                                      : (S + (size_t)ga * HSIDE + c);
            __builtin_amdgcn_global_load_lds(
                (glob_void*)src, (lds_void*)(As + (size_t)chi * 8), 16, 0, 0);
            int gb = r;            // N=128, colBase=0
            __builtin_amdgcn_global_load_lds(
                (glob_void*)(BT + (size_t)gb * KD2 + k0 + c),
                (lds_void*)(Bs + (size_t)chi * 8), 16, 0, 0);
        }
        __syncthreads();

        #pragma unroll
        for (int kk = 0; kk < 2; ++kk) {
            bf16x8 af[4], bfr[4];
            const int cb2 = (kk * 32 + (lane >> 4) * 8) * 2;
            #pragma unroll
            for (int mi = 0; mi < 4; ++mi) {
                int r = wr * 64 + mi * 16 + (lane & 15);
                int off = (r * 128 + cb2) ^ ((r & 7) << 4);
                af[mi] = *(const bf16x8*)((const char*)As + off);
            }
            #pragma unroll
            for (int nj = 0; nj < 4; ++nj) {
                int r = wc * 64 + nj * 16 + (lane & 15);
                int off = (r * 128 + cb2) ^ ((r & 7) << 4);
                bfr[nj] = *(const bf16x8*)((const char*)Bs + off);
            }
            #pragma unroll
            for (int mi = 0; mi < 4; ++mi)
                #pragma unroll
                for (int nj = 0; nj < 4; ++nj)
                    acc[mi][nj] = __builtin_amdgcn_mfma_f32_16x16x32_bf16(
                        af[mi], bfr[nj], acc[mi][nj], 0, 0, 0);
        }
        __syncthreads();
    }

    #pragma unroll
    for (int mi = 0; mi < 4; ++mi) {
        #pragma unroll
        for (int q = 0; q < 4; ++q) {
            int gr = rowBase + wr * 64 + mi * 16 + (lane >> 4) * 4 + q;
            if (gr >= M) continue;
            #pragma unroll
            for (int nj = 0; nj < 4; ++nj) {
                int gc = wc * 64 + nj * 16 + (lane & 15);
                C[(size_t)gr * DENC + gc] = f2bf(acc[mi][nj][q]);
            }
        }
    }
}

// ---------------------------------------------------------------------------
// prep_k: fused {binhist | side dense | weight cvts | input cvt}. All
// independent; LDS is a union (11.8KB) so binhist occupancy is unchanged.
#define SBM 64
#define SBK 16
__global__ __launch_bounds__(256) void prep_k(
    const int* __restrict__ su, const int* __restrict__ si,
    const float* __restrict__ sv,
    int* __restrict__ bCnt, ull* __restrict__ bktU, ull* __restrict__ bktV,
    const float* __restrict__ W_enc, ushort* __restrict__ WencT2,
    const float* __restrict__ Wu2, const float* __restrict__ Wi2,
    ushort* __restrict__ W2ufT, ushort* __restrict__ W2ifT,
    const float* __restrict__ dec_W, ushort* __restrict__ decbf,
    const float* __restrict__ u_in, const float* __restrict__ v_in,
    ushort* __restrict__ u_bf, ushort* __restrict__ v_bf,
    const float* __restrict__ uS, const float* __restrict__ vS,
    const float* __restrict__ Wu1, const float* __restrict__ bu1,
    const float* __restrict__ Wi1, const float* __restrict__ bi1,
    ushort* __restrict__ sideU, ushort* __restrict__ sideV)
{
    __shared__ __align__(16) char smem[2 * NBT * 4];   // 11760 B union
    const int bid = blockIdx.x;
    const int t = threadIdx.x;

    if (bid < GBIN) {
        // ---- level-1 binning (LDS-only histogram + range reservation) ----
        int* lcnt  = (int*)smem;
        int* lbase = (int*)(smem + NBT * 4);
        const int e0 = bid * CHUNK;
        for (int i = t; i < NBT; i += 256) lcnt[i] = 0;
        __syncthreads();
        for (int i = t; i < CHUNK; i += 256) {
            int e = e0 + i;
            if (e >= NEDGE) break;
            int k = e / ESUP;
            int r = su[e], c = si[e];
            atomicAdd(&lcnt[k * RU + (r >> 9)], 1);
            atomicAdd(&lcnt[NBU + k * RV + (c >> 9)], 1);
        }
        __syncthreads();
        for (int i = t; i < NBT; i += 256) {
            int n = lcnt[i];
            lbase[i] = n ? atomicAdd(&bCnt[i], n) : 0;
        }
        __syncthreads();
        for (int i = t; i < NBT; i += 256) lcnt[i] = 0;
        __syncthreads();
        for (int i = t; i < CHUNK; i += 256) {
            int e = e0 + i;
            if (e >= NEDGE) break;
            int k = e / ESUP;
            int r = su[e], c = si[e];
            ull vb = (ull)(unsigned)__float_as_int(sv[e]) << 32;
            int bu = k * RU + (r >> 9);
            int pu = lbase[bu] + atomicAdd(&lcnt[bu], 1);
            if (pu < CAPU)
                bktU[(size_t)bu * CAPU + pu] = vb | (uint)(((r & 511) << 16) | c);
            int bv = NBU + k * RV + (c >> 9);
            int pv = lbase[bv] + atomicAdd(&lcnt[bv], 1);
            if (pv < CAPV)
                bktV[(size_t)(bv - NBU) * CAPV + pv] = vb | (uint)(((c & 511) << 17) | r);
        }
    } else if (bid < PBS) {
        // ---- side dense: sideBuf[gr][gc] = bf16(relu(uS@Wu1 + bu1)) ----
        float (*As)[SBM + 4] = (float (*)[SBM + 4])smem;
        float (*Bs)[SBM + 4] = (float (*)[SBM + 4])(smem + SBK * (SBM + 4) * 4);
        int b = bid - GBIN;
        const float *A, *B, *bias; ushort* O; int M, rowBase;
        if (b < GU64) { A = uS; B = Wu1; bias = bu1; O = sideU; M = NU; rowBase = b * 64; }
        else { A = vS; B = Wi1; bias = bi1; O = sideV; M = NV; rowBase = (b - GU64) * 64; }
        const int ty = t >> 4, tx = t & 15;
        float acc[4][4] = {};
        for (int k0 = 0; k0 < DSIDE; k0 += SBK) {
            #pragma unroll
            for (int p = 0; p < 4; ++p) {
                int r = p * 16 + (t >> 4), kk = t & 15;
                int gr = rowBase + r, gk = k0 + kk;
                As[kk][r] = (gr < M) ? A[(size_t)gr * DSIDE + gk] : 0.f;
            }
            #pragma unroll
            for (int p = 0; p < 4; ++p) {
                int kk = p * 4 + (t >> 6), j = t & 63;
                Bs[kk][j] = B[(size_t)(k0 + kk) * HSIDE + j];
            }
            __syncthreads();
            #pragma unroll
            for (int kk = 0; kk < SBK; ++kk) {
                float4 a4 = *reinterpret_cast<const float4*>(&As[kk][ty * 4]);
                float4 b4 = *reinterpret_cast<const float4*>(&Bs[kk][tx * 4]);
                float aa[4] = {a4.x, a4.y, a4.z, a4.w};
                float bb[4] = {b4.x, b4.y, b4.z, b4.w};
                #pragma unroll
                for (int i = 0; i < 4; ++i)
                    #pragma unroll
                    for (int j = 0; j < 4; ++j)
                        acc[i][j] = fmaf(aa[i], bb[j], acc[i][j]);
            }
            __syncthreads();
        }
        #pragma unroll
        for (int i = 0; i < 4; ++i) {
            int gr = rowBase + ty * 4 + i;
            if (gr >= M) continue;
            #pragma unroll
            for (int j = 0; j < 4; ++j) {
                int gc = tx * 4 + j;
                O[(size_t)gr * HSIDE + gc] = f2bf(fmaxf(acc[i][j] + bias[gc], 0.f));
            }
        }
    } else if (bid < PB1) {
        // ---- WencT2[n'][d]: k=n'>>7, f=n'&127; f<100 ? W_enc[k][d][f] : 0 ----
        int idx = (bid - PBS) * 256 + t;             // 640*512
        int np = idx >> 9, d = idx & 511;
        int k = np >> 7, f = np & 127;
        float v = (f < FSUP) ? W_enc[((size_t)k * DIN + d) * FSUP + f] : 0.f;
        WencT2[idx] = f2bf(v);
    } else if (bid < PB3) {
        // ---- W2fT[j][c]: c<500 -> W2[c][j]; 500..511 -> 0; 512..575 -> W2[c-12][j]
        int which = (bid < PB2) ? 0 : 1;
        int idx = (bid - (which ? PB2 : PB1)) * 256 + t;   // 128*576
        const float* W = which ? Wi2 : Wu2;
        ushort* out = which ? W2ifT : W2ufT;
        int j = idx / KD2, c = idx - j * KD2;
        float v = 0.f;
        if (c < DGCN) v = W[(size_t)c * DENC + j];
        else if (c >= XW) v = W[(size_t)(c - 12) * DENC + j];
        out[idx] = f2bf(v);
    } else if (bid < PB4) {
        // ---- decbf = bf16(dec_W) flat ----
        long i = ((long)(bid - PB3) * 256 + t) * 4;
        if (i < (long)NBAS * DENC * DENC) {
            float4 v = *(const float4*)(dec_W + i);
            ushort4 o;
            o.x = f2bf(v.x); o.y = f2bf(v.y); o.z = f2bf(v.z); o.w = f2bf(v.w);
            *(ushort4*)(decbf + i) = o;
        }
    } else {
        // ---- input conversion u_in/v_in -> bf16 ----
        long i = ((long)(bid - PB4) * 256 + t) * 4;
        const long nu = (long)NU * 512;
        const float* src; ushort* dst;
        if (i < nu) { src = u_in; dst = u_bf; }
        else {
            i -= nu;
            if (i >= (long)NV * 512) return;
            src = v_in; dst = v_bf;
        }
        float4 v = *(const float4*)(src + i);
        ushort4 o;
        o.x = f2bf(v.x); o.y = f2bf(v.y); o.z = f2bf(v.z); o.w = f2bf(v.w);
        *(ushort4*)(dst + i) = o;
    }
}

// ---------------------------------------------------------------------------
// Level-2: in-bucket LDS counting sort -> fully sequential CSR writes AND
// rowPtr derivation. Bucket bases computed in-block by scanning bCnt.
__global__ __launch_bounds__(256) void scat3_k(
    const int* __restrict__ bCnt,
    const ull* __restrict__ bktU, const ull* __restrict__ bktV,
    int* __restrict__ rowPtrU, int* __restrict__ rowPtrV,
    ull* __restrict__ eU, ull* __restrict__ eV)
{
    __shared__ ull stage[CAPV];          // 40 KB
    __shared__ int cnt[BNODE];
    __shared__ int rowOff[BNODE];
    __shared__ int part[256];
    __shared__ int bbl[NBT];             // bucket bases (in-block scan)
    const int t = threadIdx.x;
    const int b = blockIdx.x;
    const int isU = (b < NBU);

    // ---- in-block exclusive scan of bCnt -> bbl ----
    {
        const int PER = (NBT + 255) / 256;   // 6
        int loc[6]; int ssum = 0;
        #pragma unroll
        for (int i = 0; i < PER; ++i) {
            int idx = t * PER + i;
            loc[i] = (idx < NBT) ? bCnt[idx] : 0;
            ssum += loc[i];
        }
        part[t] = ssum; __syncthreads();
        for (int off = 1; off < 256; off <<= 1) {
            int add = (t >= off) ? part[t - off] : 0;
            __syncthreads();
            part[t] += add;
            __syncthreads();
        }
        int bb = part[t] - ssum;
        int run = 0;
        #pragma unroll
        for (int i = 0; i < PER; ++i) {
            int idx = t * PER + i;
            if (idx < NBT) bbl[idx] = bb + run;
            run += loc[i];
        }
        __syncthreads();
    }
    if (b == 0 && t == 0) {
        rowPtrU[KSUP * NU] = NEDGE;
        rowPtrV[KSUP * NV] = NEDGE;
    }

    const ull* src;
    int n, k, baseN, base, NN;
    int* rp;
    if (isU) {
        k = b / RU; baseN = (b % RU) << 9;
        src = bktU + (size_t)b * CAPU;
        n = bCnt[b]; if (n > CAPU) n = CAPU;
        base = bbl[b]; NN = NU; rp = rowPtrU;
    } else {
        int bb2 = b - NBU;
        k = bb2 / RV; baseN = (bb2 % RV) << 9;
        src = bktV + (size_t)bb2 * CAPV;
        n = bCnt[b]; if (n > CAPV) n = CAPV;
        base = bbl[b] - NEDGE; NN = NV; rp = rowPtrV;
    }

    for (int i = t; i < BNODE; i += 256) cnt[i] = 0;
    __syncthreads();

    for (int i = t; i < n; i += 256) {
        ull en = __builtin_nontemporal_load(&src[i]);
        uint w0 = (uint)en;
        int local = isU ? (int)(w0 >> 16) : (int)(w0 >> 17);
        atomicAdd(&cnt[local], 1);
    }
    __syncthreads();

    int c0 = cnt[2 * t], c1 = cnt[2 * t + 1];
    int s = c0 + c1;
    part[t] = s;
    __syncthreads();
    for (int off = 1; off < 256; off <<= 1) {
        int add = (t >= off) ? part[t - off] : 0;
        __syncthreads();
        part[t] += add;
        __syncthreads();
    }
    int excl = part[t] - s;
    cnt[2 * t] = excl;          rowOff[2 * t] = excl;
    cnt[2 * t + 1] = excl + c0; rowOff[2 * t + 1] = excl + c0;
    __syncthreads();

    for (int i = t; i < BNODE; i += 256) {
        int node = baseN + i;
        if (node < NN) rp[k * NN + node] = base + rowOff[i];
    }

    for (int i = t; i < n; i += 256) {
        ull en = __builtin_nontemporal_load(&src[i]);
        uint w0 = (uint)en;
        int local; uint off4;
        if (isU) { local = (int)(w0 >> 16); off4 = (w0 & 0xFFFF) * (TMPW * 2); }
        else     { local = (int)(w0 >> 17); off4 = (w0 & 0x1FFFF) * (TMPW * 2); }
        int p = atomicAdd(&cnt[local], 1);
        stage[p] = (en & 0xFFFFFFFF00000000ull) | off4;
    }
    __syncthreads();

    ull* dst = (isU ? eU : eV) + base;
    for (int i = t; i < n; i += 256)
        __builtin_nontemporal_store(stage[i], &dst[i]);
}

// ---------------------------------------------------------------------------
// Merged-support CSR aggregation helper: ONE wave per node, supports
// [K0,K0+NK) in one interleaved latency chain. NT edge loads (stream-once).
template<int K0, int NK, int B, int NNODE>
__device__ __forceinline__ void agg_do(
    const int* __restrict__ rowPtr, const ull* __restrict__ eArr,
    const char* __restrict__ tSrc, int n, uint lane4,
    float* __restrict__ a0, float* __restrict__ a1)
{
    int s[NK], d[NK];
    #pragma unroll
    for (int kk = 0; kk < NK; ++kk) {
        int g = (K0 + kk) * NNODE + n;
        int ss = rowPtr[g];
        int ee = rowPtr[g + 1];     // sentinel covers the last segment
        s[kk] = ss; d[kk] = ee - ss;
    }
    uint ex[NK][B], ev[NK][B], gw[NK][B];
    #pragma unroll
    for (int kk = 0; kk < NK; ++kk)
        #pragma unroll
        for (int i = 0; i < B; ++i) {
            int idx = (i < d[kk]) ? i : 0;
            ull t = __builtin_nontemporal_load(&eArr[s[kk] + idx]);
            ex[kk][i] = (i < d[kk]) ? (uint)t : 0u;
            ev[kk][i] = (uint)(t >> 32);
        }
    #pragma unroll
    for (int kk = 0; kk < NK; ++kk)
        #pragma unroll
        for (int i = 0; i < B; ++i)
            gw[kk][i] = *(const uint*)(tSrc + (ex[kk][i] + lane4 + ((uint)(K0 + kk) << 8)));
    #pragma unroll
    for (int kk = 0; kk < NK; ++kk) {
        float x0 = 0.f, x1 = 0.f;
        #pragma unroll
        for (int i = 0; i < B; ++i)
            if (i < d[kk]) {
                float v = __uint_as_float(ev[kk][i]);
                x0 = fmaf(v, lof(gw[kk][i]), x0);
                x1 = fmaf(v, hif(gw[kk][i]), x1);
            }
        a0[K0 + kk] = x0; a1[K0 + kk] = x1;
    }
    #pragma unroll
    for (int kk = 0; kk < NK; ++kk) {
        if (d[kk] > B) {            // wave-uniform branch
            uint fx[B], fv[B], g1[B];
            #pragma unroll
            for (int i = 0; i < B; ++i) {
                int idx = (B + i < d[kk]) ? B + i : B;
                ull t = __builtin_nontemporal_load(&eArr[s[kk] + idx]);
                fx[i] = (B + i < d[kk]) ? (uint)t : 0u;
                fv[i] = (uint)(t >> 32);
            }
            #pragma unroll
            for (int i = 0; i < B; ++i)
                g1[i] = *(const uint*)(tSrc + (fx[i] + lane4 + ((uint)(K0 + kk) << 8)));
            #pragma unroll
            for (int i = 0; i < B; ++i)
                if (B + i < d[kk]) {
                    float v = __uint_as_float(fv[i]);
                    a0[K0 + kk] = fmaf(v, lof(g1[i]), a0[K0 + kk]);
                    a1[K0 + kk] = fmaf(v, hif(g1[i]), a1[K0 + kk]);
                }
            for (int p = 2 * B; p < d[kk]; ++p) {
                ull t = __builtin_nontemporal_load(&eArr[s[kk] + p]);
                uint g = *(const uint*)(tSrc + ((uint)t + lane4 + ((uint)(K0 + kk) << 8)));
                float v = __uint_as_float((uint)(t >> 32));
                a0[K0 + kk] = fmaf(v, lof(g), a0[K0 + kk]);
                a1[K0 + kk] = fmaf(v, hif(g), a1[K0 + kk]);
            }
        }
    }
}

__device__ __forceinline__ void agg_store(ushort* Xrow, int lane,
                                          const float* a0, const float* a1) {
    #pragma unroll
    for (int k = 0; k < KSUP; ++k) {
        uint payload = (uint)f2bf(fmaxf(a0[k], 0.f)) |
                       ((uint)f2bf(fmaxf(a1[k], 0.f)) << 16);
        if (lane < 50)
            __builtin_nontemporal_store(payload, (uint*)(Xrow + k * FSUP) + lane);
    }
    if (lane < 6)   // zero pad cols 500..511
        __builtin_nontemporal_store(0u, (uint*)(Xrow + 500) + lane);
}

// U-direction: gathers tmpV (LDS-free; separate launch so tmpV alone is
// L3-resident — R20 lesson: merging U+V made both tables contend, +27us)
__global__ __launch_bounds__(256) void agg_u_k(
    const int* __restrict__ rowPtrU, const ull* __restrict__ eU,
    const ushort* __restrict__ tmpV, ushort* __restrict__ Xu)
{
    const int lane = threadIdx.x & 63;
    const int n = blockIdx.x * 4 + (threadIdx.x >> 6);
    const uint lane4 = (uint)(((lane < 50) ? lane : 49) << 2);
    float a0[KSUP], a1[KSUP];
    agg_do<0, KSUP, 4, NU>(rowPtrU, eU, (const char*)tmpV, n, lane4, a0, a1);
    agg_store(Xu + (size_t)n * XW, lane, a0, a1);
}

// V-direction: gathers tmpU (LDS-free)
__global__ __launch_bounds__(256) void agg_v_k(
    const int* __restrict__ rowPtrV, const ull* __restrict__ eV,
    const ushort* __restrict__ tmpU, ushort* __restrict__ Xv)
{
    const int lane = threadIdx.x & 63;
    const int n = blockIdx.x * 4 + (threadIdx.x >> 6);
    const uint lane4 = (uint)(((lane < 50) ? lane : 49) << 2);
    float a0[KSUP], a1[KSUP];
    agg_do<0, 3, 8, NV>(rowPtrV, eV, (const char*)tmpU, n, lane4, a0, a1);
    agg_do<3, 2, 8, NV>(rowPtrV, eV, (const char*)tmpU, n, lane4, a0, a1);
    agg_store(Xv + (size_t)n * XW, lane, a0, a1);
}

// ---------------------------------------------------------------------------
// final decoder: int2 gathers; basis[b] = dot(embU[u], Vb[v][b]); out=basis@cls
__global__ __launch_bounds__(256) void dec_k(
    const int* __restrict__ ue, const int* __restrict__ ie,
    const ushort* __restrict__ embU, const ushort* __restrict__ Vb,
    const float* __restrict__ cls, float* __restrict__ out, int nE)
{
    int e = blockIdx.x * 8 + (threadIdx.x >> 5);
    if (e >= nE) return;
    int lane = threadIdx.x & 31;
    int u = ue[e], v = ie[e];
    const int2* pu2 = (const int2*)(embU + (size_t)u * DENC);        // 32 int2
    const int2* pv2 = (const int2*)(Vb + (size_t)v * (NBAS * DENC)); // 96 int2
    int2 uu = pu2[lane];                 // cols 4l..4l+3
    int2 bb[NBAS];
    #pragma unroll
    for (int b = 0; b < NBAS; ++b) bb[b] = pv2[b * 32 + lane];
    float uxl = lof((uint)uu.x), uxh = hif((uint)uu.x);
    float uyl = lof((uint)uu.y), uyh = hif((uint)uu.y);
    float s[NBAS];
    #pragma unroll
    for (int b = 0; b < NBAS; ++b) {
        float t = lof((uint)bb[b].x) * uxl;
        t = fmaf(hif((uint)bb[b].x), uxh, t);
        t = fmaf(lof((uint)bb[b].y), uyl, t);
        s[b] = fmaf(hif((uint)bb[b].y), uyh, t);
    }
    #pragma unroll
    for (int off = 16; off; off >>= 1)
        #pragma unroll
        for (int b = 0; b < NBAS; ++b) s[b] += __shfl_xor(s[b], off, 32);
    if (lane < NCLS) {
        float o = 0.f;
        #pragma unroll
        for (int b = 0; b < NBAS; ++b) o += s[b] * cls[b * NCLS + lane];
        out[(size_t)e * NCLS + lane] = o;
    }
}

// ---------------------------------------------------------------------------
extern "C" void kernel_launch(void* const* d_in, const int* in_sizes, int n_in,
                              void* d_out, int out_size, void* d_ws, size_t ws_size,
                              hipStream_t stream) {
    const int*   sup_u  = (const int*)  d_in[0];
    const int*   sup_i  = (const int*)  d_in[1];
    const float* sup_v  = (const float*)d_in[2];
    const float* u_in   = (const float*)d_in[3];
    const float* v_in   = (const float*)d_in[4];
    const float* u_side = (const float*)d_in[5];
    const float* v_side = (const float*)d_in[6];
    const int*   ue     = (const int*)  d_in[7];
    const int*   ie     = (const int*)  d_in[8];
    const float* W_enc  = (const float*)d_in[9];
    const float* Wu1    = (const float*)d_in[10];
    const float* bu1    = (const float*)d_in[11];
    const float* Wi1    = (const float*)d_in[12];
    const float* bi1    = (const float*)d_in[13];
    const float* Wu2    = (const float*)d_in[14];
    const float* Wi2    = (const float*)d_in[15];
    const float* dec_W  = (const float*)d_in[16];
    const float* deccls = (const float*)d_in[17];

    char* ws = (char*)d_ws;
    // timeline overlays: u_bf/v_bf live ph1-2 (enc GEMM); Xu/Xv (same size)
    // written by agg in ph3 after u_bf is dead.
    ushort* u_bf   = (ushort*)(ws);                     // [NU][512] 102.4M
    ushort* v_bf   = (ushort*)(ws + 102400000LL);       // [NV][512] 51.2M
    ushort* Xu     = (ushort*)(ws);                     // [NU][512] 102.4M
    ushort* Xv     = (ushort*)(ws + 102400000LL);       // [NV][512] 51.2M
    // CSR @176M (dead after agg); rowPtr regions padded for the +1 sentinel.
    int*    rowPtrU= (int*)(ws + 179000000LL);          // 2M + 4 sentinel
    int*    rowPtrV= (int*)(ws + 181200000LL);          // 1M + 4 sentinel
    int*    bCnt   = (int*)(ws + 185810000LL);          // [1470] contiguous
    ull*    eU     = (ull*)(ws + 186000000LL);          // [2M] 16M
    ull*    eV     = (ull*)(ws + 202000000LL);          // [2M] 16M ends 218M
    // tmp @220M (dead after agg): tmpU [NU][640] 128M, tmpV [NV][640] 64M
    ushort* tmpU   = (ushort*)(ws + 220000000LL);
    ushort* tmpV   = (ushort*)(ws + 348000000LL);       // ends 412M
    // L1 buckets: overlay on tmp region (dead before encoder GEMMs write tmp)
    ull*    bktU   = (ull*)(ws + 220000000LL);          // 980*2560*8  = 20.1M
    ull*    bktV   = (ull*)(ws + 241000000LL);          // 490*5120*8  = 20.1M
    // post-agg overlays:
    ushort* embUbf = (ushort*)(ws + 176000000LL);       // [NU][128] 25.6M (over CSR)
    ushort* embVbf = (ushort*)(ws + 202000000LL);       // [NV][128] 12.8M (over eV)
    ushort* Vb     = (ushort*)(ws + 220000000LL);       // [NV][384] 38.4M (over tmp)
    // weights @412M:
    ushort* WencT2 = (ushort*)(ws + 412000000LL);       // [640][512] 0.66M
    ushort* W2ufT  = (ushort*)(ws + 413000000LL);       // [128][576] 0.15M
    ushort* W2ifT  = (ushort*)(ws + 413200000LL);       // [128][576] 0.15M
    ushort* decbf  = (ushort*)(ws + 413400000LL);       // [384][128] 0.10M
    // side buffers @413.6M (written in prep, read in d2 — own region):
    ushort* sideU  = (ushort*)(ws + 413600000LL);       // [NU][64] 12.8M
    ushort* sideV  = (ushort*)(ws + 426400000LL);       // [NV][64] 6.4M ends 432.8M

    dim3 blk(256);

    // ---- phase 1: fused prep (binhist ∥ side dense ∥ weight cvts ∥ cvt_in) ----
    hipMemsetAsync(bCnt, 0, 8192, stream);              // bucket counters
    prep_k<<<dim3(PTOT), blk, 0, stream>>>(
        sup_u, sup_i, sup_v, bCnt, bktU, bktV,
        W_enc, WencT2, Wu2, Wi2, W2ufT, W2ifT, dec_W, decbf,
        u_in, v_in, u_bf, v_bf,
        u_side, v_side, Wu1, bu1, Wi1, bi1, sideU, sideV);
    scat3_k<<<dim3(NBT), blk, 0, stream>>>(bCnt, bktU, bktV,
                                           rowPtrU, rowPtrV, eU, eV);

    // ---- phase 2: fused encoder GEMMs (bf16 A; x = col tile -> L3 reuse) ----
    gemm_enc_k<<<dim3(TMPW / 128, GU128 + GV128), blk, 0, stream>>>(
        u_bf, v_bf, WencT2, tmpU, tmpV);

    // ---- phase 3: CSR aggregation, U then V (separate launches: each
    //      gather table L3-resident alone) ----
    agg_u_k<<<dim3(NU / 4), blk, 0, stream>>>(rowPtrU, eU, tmpV, Xu);
    agg_v_k<<<dim3(NV / 4), blk, 0, stream>>>(rowPtrV, eV, tmpU, Xv);

    // ---- phase 4: fused dense2 (split A: X + sideBuf) -> emb bf16 ----
    gemm_d2_k<<<dim3(1, GU128 + GV128), blk, 0, stream>>>(
        Xu, Xv, sideU, sideV, W2ufT, W2ifT, embUbf, embVbf);

    // ---- phase 5: decoder precompute on V side: Vb = embV @ decbf^T ----
    gemm_bf16_k<<<dim3(3, GV128), blk, 0, stream>>>(embVbf, decbf, Vb, NV, 384, 128, 384);

    // ---- phase 6: final decoder over edges ----
    dec_k<<<dim3(NE / 8), blk, 0, stream>>>(ue, ie, embUbf, Vb, deccls, (float*)d_out, NE);
}

// Round 22
// 814.894 us; speedup vs baseline: 1.0315x; 1.0315x over previous
//
#include <hip/hip_runtime.h>

// Problem constants (fixed by the reference)
#define NU 100000
#define NV 50000
#define KSUP 5
#define ESUP 400000
#define NEDGE (KSUP * ESUP)   // 2,000,000
#define NE 500000
#define DIN 512
#define DGCN 500
#define FSUP 100     // DGCN / KSUP
#define DSIDE 128
#define HSIDE 64
#define DENC 128
#define NBAS 3
#define NCLS 5

#define TMPW 512     // tmp width: 5 supports x 100 packed + 12 zero pad
                     // (R22: dropped 128-col alignment padding — R7 showed
                     // gather alignment is time-neutral; saves 20% enc FLOPs)
#define XW 512       // X width: 500 gcn + 12 pad (side lives in sideBuf)
#define KD2 576      // dense2 K: 512 (X) + 64 (sideBuf)

// two-level scatter geometry (node-range = 512 so V-bucket stages in LDS)
#define BNODE 512
#define RU 196       // ceil(NU/512)
#define RV 98        // ceil(NV/512)
#define NBU (KSUP * RU)   // 980 U buckets
#define NBV (KSUP * RV)   // 490 V buckets
#define NBT (NBU + NBV)   // 1470
#define CAPU 2560    // mean 2048, +11 sigma
#define CAPV 5120    // mean 4096, +16 sigma
#define CHUNK 8192   // edges per block in binhist

// grid-partition constants
#define GU128 782    // ceil(NU/128)
#define GV128 391    // ceil(NV/128)
#define GU64 1563    // ceil(NU/64)
#define GV64 782     // ceil(NV/64)
#define GS (GU64 + GV64)           // 2345 side blocks
#define GBIN 245     // ceil(NEDGE/CHUNK)
#define PBS (GBIN + GS)            // side blocks end
#define PB1 (PBS + 1024)           // + wencT2 blocks (512*512/256)
#define PB2 (PB1 + 288)            // + W2u blocks (128*576/256)
#define PB3 (PB2 + 288)            // + W2i blocks
#define PB4 (PB3 + 48)             // + dec cvt blocks (384*128/4/256)
#define PTOT (PB4 + 75000)         // + input cvt blocks ((NU+NV)*512/4/256)

__device__ __forceinline__ ushort f2bf(float x) {
    union { float f; unsigned u; } c; c.f = x;
    unsigned r = (c.u + 0x7FFFu + ((c.u >> 16) & 1u)) >> 16;   // RNE
    return (ushort)r;
}
// unpack a u32 holding two bf16 (lo = even col, hi = odd col)
__device__ __forceinline__ float lof(uint g) { return __uint_as_float(g << 16); }
__device__ __forceinline__ float hif(uint g) { return __uint_as_float(g & 0xffff0000u); }

typedef __attribute__((ext_vector_type(4))) float f32x4;
typedef __attribute__((ext_vector_type(8))) short bf16x8;
typedef __attribute__((address_space(3))) void lds_void;
typedef const __attribute__((address_space(1))) void glob_void;
typedef unsigned long long ull;

// ---------------------------------------------------------------------------
// bf16 MFMA GEMM body: C[M,N](bf16) = A[M,K](bf16,K-major) @ BT[N,K]^T
// 128x128 tile, BK=64, 4 waves (2x2). LDS XOR-swizzled via pre-swizzled
// global source (rule #21). ONE call site per kernel (single __shared__).
__device__ __forceinline__ void gemm_body(
    const ushort* __restrict__ A, const ushort* __restrict__ BT,
    ushort* __restrict__ Cout, int M, int N, int K, int ldc,
    int rowBase, int colBase)
{
    __shared__ ushort As[128 * 64];
    __shared__ ushort Bs[128 * 64];
    const int t = threadIdx.x;
    const int lane = t & 63;
    const int w = t >> 6;
    const int wr = w >> 1, wc = w & 1;

    f32x4 acc[4][4] = {};

    for (int k0 = 0; k0 < K; k0 += 64) {
        #pragma unroll
        for (int i = 0; i < 4; ++i) {
            int chi = i * 256 + t;
            int r = chi >> 3;
            int c = (((chi >> 3) & 7) ^ (chi & 7)) * 8;
            int ga = rowBase + r; if (ga > M - 1) ga = M - 1;
            __builtin_amdgcn_global_load_lds(
                (glob_void*)(A + (size_t)ga * K + k0 + c),
                (lds_void*)(As + (size_t)chi * 8), 16, 0, 0);
            int gb = colBase + r; if (gb > N - 1) gb = N - 1;
            __builtin_amdgcn_global_load_lds(
                (glob_void*)(BT + (size_t)gb * K + k0 + c),
                (lds_void*)(Bs + (size_t)chi * 8), 16, 0, 0);
        }
        __syncthreads();

        #pragma unroll
        for (int kk = 0; kk < 2; ++kk) {
            bf16x8 af[4], bfr[4];
            const int cb2 = (kk * 32 + (lane >> 4) * 8) * 2;
            #pragma unroll
            for (int mi = 0; mi < 4; ++mi) {
                int r = wr * 64 + mi * 16 + (lane & 15);
                int off = (r * 128 + cb2) ^ ((r & 7) << 4);
                af[mi] = *(const bf16x8*)((const char*)As + off);
            }
            #pragma unroll
            for (int nj = 0; nj < 4; ++nj) {
                int r = wc * 64 + nj * 16 + (lane & 15);
                int off = (r * 128 + cb2) ^ ((r & 7) << 4);
                bfr[nj] = *(const bf16x8*)((const char*)Bs + off);
            }
            #pragma unroll
            for (int mi = 0; mi < 4; ++mi)
                #pragma unroll
                for (int nj = 0; nj < 4; ++nj)
                    acc[mi][nj] = __builtin_amdgcn_mfma_f32_16x16x32_bf16(
                        af[mi], bfr[nj], acc[mi][nj], 0, 0, 0);
        }
        __syncthreads();
    }

    #pragma unroll
    for (int mi = 0; mi < 4; ++mi) {
        #pragma unroll
        for (int q = 0; q < 4; ++q) {
            int gr = rowBase + wr * 64 + mi * 16 + (lane >> 4) * 4 + q;
            if (gr >= M) continue;
            #pragma unroll
            for (int nj = 0; nj < 4; ++nj) {
                int gc = colBase + wc * 64 + nj * 16 + (lane & 15);
                Cout[(size_t)gr * ldc + gc] = f2bf(acc[mi][nj][q]);
            }
        }
    }
}

// generic single-matrix bf16 GEMM (used for Vb precompute)
__global__ __launch_bounds__(256) void gemm_bf16_k(
    const ushort* __restrict__ A, const ushort* __restrict__ BT,
    ushort* __restrict__ Cout, int M, int N, int K, int ldc)
{
    gemm_body(A, BT, Cout, M, N, K, ldc, blockIdx.y * 128, blockIdx.x * 128);
}

// fused encoder GEMM: U rows then V rows via blockIdx.y partition
__global__ __launch_bounds__(256) void gemm_enc_k(
    const ushort* __restrict__ u_bf, const ushort* __restrict__ v_bf,
    const ushort* __restrict__ WencT2,
    ushort* __restrict__ tmpU, ushort* __restrict__ tmpV)
{
    int y = blockIdx.y;
    const ushort* A; ushort* C; int M, rowBase;
    if (y < GU128) { A = u_bf; C = tmpU; M = NU; rowBase = y * 128; }
    else           { A = v_bf; C = tmpV; M = NV; rowBase = (y - GU128) * 128; }
    gemm_body(A, WencT2, C, M, TMPW, 512, TMPW, rowBase, blockIdx.x * 128);
}

// fused dense2 GEMM with SPLIT A: k0<512 reads X[M][512]; k0==512 reads
// sideBuf[M][64]. K=576, N=128. W2fT cols remapped to match (see prep_k).
__global__ __launch_bounds__(256) void gemm_d2_k(
    const ushort* __restrict__ Xu, const ushort* __restrict__ Xv,
    const ushort* __restrict__ sideU, const ushort* __restrict__ sideV,
    const ushort* __restrict__ W2u, const ushort* __restrict__ W2i,
    ushort* __restrict__ embU, ushort* __restrict__ embV)
{
    __shared__ ushort As[128 * 64];
    __shared__ ushort Bs[128 * 64];
    int y = blockIdx.y;
    const ushort *X, *S, *BT; ushort* C; int M, rowBase;
    if (y < GU128) { X = Xu; S = sideU; BT = W2u; C = embU; M = NU; rowBase = y * 128; }
    else { X = Xv; S = sideV; BT = W2i; C = embV; M = NV; rowBase = (y - GU128) * 128; }

    const int t = threadIdx.x;
    const int lane = t & 63;
    const int w = t >> 6;
    const int wr = w >> 1, wc = w & 1;

    f32x4 acc[4][4] = {};

    for (int k0 = 0; k0 < KD2; k0 += 64) {
        const bool fromX = (k0 < XW);
        #pragma unroll
        for (int i = 0; i < 4; ++i) {
            int chi = i * 256 + t;
            int r = chi >> 3;
            int c = (((chi >> 3) & 7) ^ (chi & 7)) * 8;
            int ga = rowBase + r; if (ga > M - 1) ga = M - 1;
            const ushort* src = fromX ? (X + (size_t)ga * XW + k0 + c)
                                      : (S + (size_t)ga * HSIDE + c);
            __builtin_amdgcn_global_load_lds(
                (glob_void*)src, (lds_void*)(As + (size_t)chi * 8), 16, 0, 0);
            int gb = r;            // N=128, colBase=0
            __builtin_amdgcn_global_load_lds(
                (glob_void*)(BT + (size_t)gb * KD2 + k0 + c),
                (lds_void*)(Bs + (size_t)chi * 8), 16, 0, 0);
        }
        __syncthreads();

        #pragma unroll
        for (int kk = 0; kk < 2; ++kk) {
            bf16x8 af[4], bfr[4];
            const int cb2 = (kk * 32 + (lane >> 4) * 8) * 2;
            #pragma unroll
            for (int mi = 0; mi < 4; ++mi) {
                int r = wr * 64 + mi * 16 + (lane & 15);
                int off = (r * 128 + cb2) ^ ((r & 7) << 4);
                af[mi] = *(const bf16x8*)((const char*)As + off);
            }
            #pragma unroll
            for (int nj = 0; nj < 4; ++nj) {
                int r = wc * 64 + nj * 16 + (lane & 15);
                int off = (r * 128 + cb2) ^ ((r & 7) << 4);
                bfr[nj] = *(const bf16x8*)((const char*)Bs + off);
            }
            #pragma unroll
            for (int mi = 0; mi < 4; ++mi)
                #pragma unroll
                for (int nj = 0; nj < 4; ++nj)
                    acc[mi][nj] = __builtin_amdgcn_mfma_f32_16x16x32_bf16(
                        af[mi], bfr[nj], acc[mi][nj], 0, 0, 0);
        }
        __syncthreads();
    }

    #pragma unroll
    for (int mi = 0; mi < 4; ++mi) {
        #pragma unroll
        for (int q = 0; q < 4; ++q) {
            int gr = rowBase + wr * 64 + mi * 16 + (lane >> 4) * 4 + q;
            if (gr >= M) continue;
            #pragma unroll
            for (int nj = 0; nj < 4; ++nj) {
                int gc = wc * 64 + nj * 16 + (lane & 15);
                C[(size_t)gr * DENC + gc] = f2bf(acc[mi][nj][q]);
            }
        }
    }
}

// ---------------------------------------------------------------------------
// prep_k: fused {binhist | side dense | weight cvts | input cvt}. All
// independent; LDS is a union (11.8KB) so binhist occupancy is unchanged.
#define SBM 64
#define SBK 16
__global__ __launch_bounds__(256) void prep_k(
    const int* __restrict__ su, const int* __restrict__ si,
    const float* __restrict__ sv,
    int* __restrict__ bCnt, ull* __restrict__ bktU, ull* __restrict__ bktV,
    const float* __restrict__ W_enc, ushort* __restrict__ WencT2,
    const float* __restrict__ Wu2, const float* __restrict__ Wi2,
    ushort* __restrict__ W2ufT, ushort* __restrict__ W2ifT,
    const float* __restrict__ dec_W, ushort* __restrict__ decbf,
    const float* __restrict__ u_in, const float* __restrict__ v_in,
    ushort* __restrict__ u_bf, ushort* __restrict__ v_bf,
    const float* __restrict__ uS, const float* __restrict__ vS,
    const float* __restrict__ Wu1, const float* __restrict__ bu1,
    const float* __restrict__ Wi1, const float* __restrict__ bi1,
    ushort* __restrict__ sideU, ushort* __restrict__ sideV)
{
    __shared__ __align__(16) char smem[2 * NBT * 4];   // 11760 B union
    const int bid = blockIdx.x;
    const int t = threadIdx.x;

    if (bid < GBIN) {
        // ---- level-1 binning (LDS-only histogram + range reservation) ----
        int* lcnt  = (int*)smem;
        int* lbase = (int*)(smem + NBT * 4);
        const int e0 = bid * CHUNK;
        for (int i = t; i < NBT; i += 256) lcnt[i] = 0;
        __syncthreads();
        for (int i = t; i < CHUNK; i += 256) {
            int e = e0 + i;
            if (e >= NEDGE) break;
            int k = e / ESUP;
            int r = su[e], c = si[e];
            atomicAdd(&lcnt[k * RU + (r >> 9)], 1);
            atomicAdd(&lcnt[NBU + k * RV + (c >> 9)], 1);
        }
        __syncthreads();
        for (int i = t; i < NBT; i += 256) {
            int n = lcnt[i];
            lbase[i] = n ? atomicAdd(&bCnt[i], n) : 0;
        }
        __syncthreads();
        for (int i = t; i < NBT; i += 256) lcnt[i] = 0;
        __syncthreads();
        for (int i = t; i < CHUNK; i += 256) {
            int e = e0 + i;
            if (e >= NEDGE) break;
            int k = e / ESUP;
            int r = su[e], c = si[e];
            ull vb = (ull)(unsigned)__float_as_int(sv[e]) << 32;
            int bu = k * RU + (r >> 9);
            int pu = lbase[bu] + atomicAdd(&lcnt[bu], 1);
            if (pu < CAPU)
                bktU[(size_t)bu * CAPU + pu] = vb | (uint)(((r & 511) << 16) | c);
            int bv = NBU + k * RV + (c >> 9);
            int pv = lbase[bv] + atomicAdd(&lcnt[bv], 1);
            if (pv < CAPV)
                bktV[(size_t)(bv - NBU) * CAPV + pv] = vb | (uint)(((c & 511) << 17) | r);
        }
    } else if (bid < PBS) {
        // ---- side dense: sideBuf[gr][gc] = bf16(relu(uS@Wu1 + bu1)) ----
        float (*As)[SBM + 4] = (float (*)[SBM + 4])smem;
        float (*Bs)[SBM + 4] = (float (*)[SBM + 4])(smem + SBK * (SBM + 4) * 4);
        int b = bid - GBIN;
        const float *A, *B, *bias; ushort* O; int M, rowBase;
        if (b < GU64) { A = uS; B = Wu1; bias = bu1; O = sideU; M = NU; rowBase = b * 64; }
        else { A = vS; B = Wi1; bias = bi1; O = sideV; M = NV; rowBase = (b - GU64) * 64; }
        const int ty = t >> 4, tx = t & 15;
        float acc[4][4] = {};
        for (int k0 = 0; k0 < DSIDE; k0 += SBK) {
            #pragma unroll
            for (int p = 0; p < 4; ++p) {
                int r = p * 16 + (t >> 4), kk = t & 15;
                int gr = rowBase + r, gk = k0 + kk;
                As[kk][r] = (gr < M) ? A[(size_t)gr * DSIDE + gk] : 0.f;
            }
            #pragma unroll
            for (int p = 0; p < 4; ++p) {
                int kk = p * 4 + (t >> 6), j = t & 63;
                Bs[kk][j] = B[(size_t)(k0 + kk) * HSIDE + j];
            }
            __syncthreads();
            #pragma unroll
            for (int kk = 0; kk < SBK; ++kk) {
                float4 a4 = *reinterpret_cast<const float4*>(&As[kk][ty * 4]);
                float4 b4 = *reinterpret_cast<const float4*>(&Bs[kk][tx * 4]);
                float aa[4] = {a4.x, a4.y, a4.z, a4.w};
                float bb[4] = {b4.x, b4.y, b4.z, b4.w};
                #pragma unroll
                for (int i = 0; i < 4; ++i)
                    #pragma unroll
                    for (int j = 0; j < 4; ++j)
                        acc[i][j] = fmaf(aa[i], bb[j], acc[i][j]);
            }
            __syncthreads();
        }
        #pragma unroll
        for (int i = 0; i < 4; ++i) {
            int gr = rowBase + ty * 4 + i;
            if (gr >= M) continue;
            #pragma unroll
            for (int j = 0; j < 4; ++j) {
                int gc = tx * 4 + j;
                O[(size_t)gr * HSIDE + gc] = f2bf(fmaxf(acc[i][j] + bias[gc], 0.f));
            }
        }
    } else if (bid < PB1) {
        // ---- WencT2[n'][d], n' in [0,512): n'<500 -> W_enc[n'/100][d][n'%100],
        //      pad n' in [500,512) -> 0 ----
        int idx = (bid - PBS) * 256 + t;             // 512*512
        int np = idx >> 9, d = idx & 511;
        float v = 0.f;
        if (np < DGCN) {
            int k = np / FSUP, f = np - k * FSUP;
            v = W_enc[((size_t)k * DIN + d) * FSUP + f];
        }
        WencT2[idx] = f2bf(v);
    } else if (bid < PB3) {
        // ---- W2fT[j][c]: c<500 -> W2[c][j]; 500..511 -> 0; 512..575 -> W2[c-12][j]
        int which = (bid < PB2) ? 0 : 1;
        int idx = (bid - (which ? PB2 : PB1)) * 256 + t;   // 128*576
        const float* W = which ? Wi2 : Wu2;
        ushort* out = which ? W2ifT : W2ufT;
        int j = idx / KD2, c = idx - j * KD2;
        float v = 0.f;
        if (c < DGCN) v = W[(size_t)c * DENC + j];
        else if (c >= XW) v = W[(size_t)(c - 12) * DENC + j];
        out[idx] = f2bf(v);
    } else if (bid < PB4) {
        // ---- decbf = bf16(dec_W) flat ----
        long i = ((long)(bid - PB3) * 256 + t) * 4;
        if (i < (long)NBAS * DENC * DENC) {
            float4 v = *(const float4*)(dec_W + i);
            ushort4 o;
            o.x = f2bf(v.x); o.y = f2bf(v.y); o.z = f2bf(v.z); o.w = f2bf(v.w);
            *(ushort4*)(decbf + i) = o;
        }
    } else {
        // ---- input conversion u_in/v_in -> bf16 ----
        long i = ((long)(bid - PB4) * 256 + t) * 4;
        const long nu = (long)NU * 512;
        const float* src; ushort* dst;
        if (i < nu) { src = u_in; dst = u_bf; }
        else {
            i -= nu;
            if (i >= (long)NV * 512) return;
            src = v_in; dst = v_bf;
        }
        float4 v = *(const float4*)(src + i);
        ushort4 o;
        o.x = f2bf(v.x); o.y = f2bf(v.y); o.z = f2bf(v.z); o.w = f2bf(v.w);
        *(ushort4*)(dst + i) = o;
    }
}

// ---------------------------------------------------------------------------
// Level-2: in-bucket LDS counting sort -> fully sequential CSR writes AND
// rowPtr derivation. Bucket bases computed in-block by scanning bCnt.
__global__ __launch_bounds__(256) void scat3_k(
    const int* __restrict__ bCnt,
    const ull* __restrict__ bktU, const ull* __restrict__ bktV,
    int* __restrict__ rowPtrU, int* __restrict__ rowPtrV,
    ull* __restrict__ eU, ull* __restrict__ eV)
{
    __shared__ ull stage[CAPV];          // 40 KB
    __shared__ int cnt[BNODE];
    __shared__ int rowOff[BNODE];
    __shared__ int part[256];
    __shared__ int bbl[NBT];             // bucket bases (in-block scan)
    const int t = threadIdx.x;
    const int b = blockIdx.x;
    const int isU = (b < NBU);

    // ---- in-block exclusive scan of bCnt -> bbl ----
    {
        const int PER = (NBT + 255) / 256;   // 6
        int loc[6]; int ssum = 0;
        #pragma unroll
        for (int i = 0; i < PER; ++i) {
            int idx = t * PER + i;
            loc[i] = (idx < NBT) ? bCnt[idx] : 0;
            ssum += loc[i];
        }
        part[t] = ssum; __syncthreads();
        for (int off = 1; off < 256; off <<= 1) {
            int add = (t >= off) ? part[t - off] : 0;
            __syncthreads();
            part[t] += add;
            __syncthreads();
        }
        int bb = part[t] - ssum;
        int run = 0;
        #pragma unroll
        for (int i = 0; i < PER; ++i) {
            int idx = t * PER + i;
            if (idx < NBT) bbl[idx] = bb + run;
            run += loc[i];
        }
        __syncthreads();
    }
    if (b == 0 && t == 0) {
        rowPtrU[KSUP * NU] = NEDGE;
        rowPtrV[KSUP * NV] = NEDGE;
    }

    const ull* src;
    int n, k, baseN, base, NN;
    int* rp;
    if (isU) {
        k = b / RU; baseN = (b % RU) << 9;
        src = bktU + (size_t)b * CAPU;
        n = bCnt[b]; if (n > CAPU) n = CAPU;
        base = bbl[b]; NN = NU; rp = rowPtrU;
    } else {
        int bb2 = b - NBU;
        k = bb2 / RV; baseN = (bb2 % RV) << 9;
        src = bktV + (size_t)bb2 * CAPV;
        n = bCnt[b]; if (n > CAPV) n = CAPV;
        base = bbl[b] - NEDGE; NN = NV; rp = rowPtrV;
    }

    for (int i = t; i < BNODE; i += 256) cnt[i] = 0;
    __syncthreads();

    for (int i = t; i < n; i += 256) {
        ull en = __builtin_nontemporal_load(&src[i]);
        uint w0 = (uint)en;
        int local = isU ? (int)(w0 >> 16) : (int)(w0 >> 17);
        atomicAdd(&cnt[local], 1);
    }
    __syncthreads();

    int c0 = cnt[2 * t], c1 = cnt[2 * t + 1];
    int s = c0 + c1;
    part[t] = s;
    __syncthreads();
    for (int off = 1; off < 256; off <<= 1) {
        int add = (t >= off) ? part[t - off] : 0;
        __syncthreads();
        part[t] += add;
        __syncthreads();
    }
    int excl = part[t] - s;
    cnt[2 * t] = excl;          rowOff[2 * t] = excl;
    cnt[2 * t + 1] = excl + c0; rowOff[2 * t + 1] = excl + c0;
    __syncthreads();

    for (int i = t; i < BNODE; i += 256) {
        int node = baseN + i;
        if (node < NN) rp[k * NN + node] = base + rowOff[i];
    }

    for (int i = t; i < n; i += 256) {
        ull en = __builtin_nontemporal_load(&src[i]);
        uint w0 = (uint)en;
        int local; uint off4;
        if (isU) { local = (int)(w0 >> 16); off4 = (w0 & 0xFFFF) * (TMPW * 2); }
        else     { local = (int)(w0 >> 17); off4 = (w0 & 0x1FFFF) * (TMPW * 2); }
        int p = atomicAdd(&cnt[local], 1);
        stage[p] = (en & 0xFFFFFFFF00000000ull) | off4;
    }
    __syncthreads();

    ull* dst = (isU ? eU : eV) + base;
    for (int i = t; i < n; i += 256)
        __builtin_nontemporal_store(stage[i], &dst[i]);
}

// ---------------------------------------------------------------------------
// Merged-support CSR aggregation helper: ONE wave per node, supports
// [K0,K0+NK) in one interleaved latency chain. NT edge loads (stream-once).
// k-slice byte offset is k*200 (packed 100-col slices).
template<int K0, int NK, int B, int NNODE>
__device__ __forceinline__ void agg_do(
    const int* __restrict__ rowPtr, const ull* __restrict__ eArr,
    const char* __restrict__ tSrc, int n, uint lane4,
    float* __restrict__ a0, float* __restrict__ a1)
{
    int s[NK], d[NK];
    #pragma unroll
    for (int kk = 0; kk < NK; ++kk) {
        int g = (K0 + kk) * NNODE + n;
        int ss = rowPtr[g];
        int ee = rowPtr[g + 1];     // sentinel covers the last segment
        s[kk] = ss; d[kk] = ee - ss;
    }
    uint ex[NK][B], ev[NK][B], gw[NK][B];
    #pragma unroll
    for (int kk = 0; kk < NK; ++kk)
        #pragma unroll
        for (int i = 0; i < B; ++i) {
            int idx = (i < d[kk]) ? i : 0;
            ull t = __builtin_nontemporal_load(&eArr[s[kk] + idx]);
            ex[kk][i] = (i < d[kk]) ? (uint)t : 0u;
            ev[kk][i] = (uint)(t >> 32);
        }
    #pragma unroll
    for (int kk = 0; kk < NK; ++kk)
        #pragma unroll
        for (int i = 0; i < B; ++i)
            gw[kk][i] = *(const uint*)(tSrc + (ex[kk][i] + lane4 + (uint)((K0 + kk) * 200)));
    #pragma unroll
    for (int kk = 0; kk < NK; ++kk) {
        float x0 = 0.f, x1 = 0.f;
        #pragma unroll
        for (int i = 0; i < B; ++i)
            if (i < d[kk]) {
                float v = __uint_as_float(ev[kk][i]);
                x0 = fmaf(v, lof(gw[kk][i]), x0);
                x1 = fmaf(v, hif(gw[kk][i]), x1);
            }
        a0[K0 + kk] = x0; a1[K0 + kk] = x1;
    }
    #pragma unroll
    for (int kk = 0; kk < NK; ++kk) {
        if (d[kk] > B) {            // wave-uniform branch
            uint fx[B], fv[B], g1[B];
            #pragma unroll
            for (int i = 0; i < B; ++i) {
                int idx = (B + i < d[kk]) ? B + i : B;
                ull t = __builtin_nontemporal_load(&eArr[s[kk] + idx]);
                fx[i] = (B + i < d[kk]) ? (uint)t : 0u;
                fv[i] = (uint)(t >> 32);
            }
            #pragma unroll
            for (int i = 0; i < B; ++i)
                g1[i] = *(const uint*)(tSrc + (fx[i] + lane4 + (uint)((K0 + kk) * 200)));
            #pragma unroll
            for (int i = 0; i < B; ++i)
                if (B + i < d[kk]) {
                    float v = __uint_as_float(fv[i]);
                    a0[K0 + kk] = fmaf(v, lof(g1[i]), a0[K0 + kk]);
                    a1[K0 + kk] = fmaf(v, hif(g1[i]), a1[K0 + kk]);
                }
            for (int p = 2 * B; p < d[kk]; ++p) {
                ull t = __builtin_nontemporal_load(&eArr[s[kk] + p]);
                uint g = *(const uint*)(tSrc + ((uint)t + lane4 + (uint)((K0 + kk) * 200)));
                float v = __uint_as_float((uint)(t >> 32));
                a0[K0 + kk] = fmaf(v, lof(g), a0[K0 + kk]);
                a1[K0 + kk] = fmaf(v, hif(g), a1[K0 + kk]);
            }
        }
    }
}

__device__ __forceinline__ void agg_store(ushort* Xrow, int lane,
                                          const float* a0, const float* a1) {
    #pragma unroll
    for (int k = 0; k < KSUP; ++k) {
        uint payload = (uint)f2bf(fmaxf(a0[k], 0.f)) |
                       ((uint)f2bf(fmaxf(a1[k], 0.f)) << 16);
        if (lane < 50)
            __builtin_nontemporal_store(payload, (uint*)(Xrow + k * FSUP) + lane);
    }
    if (lane < 6)   // zero pad cols 500..511
        __builtin_nontemporal_store(0u, (uint*)(Xrow + 500) + lane);
}

// U-direction: gathers tmpV (LDS-free; separate launch so tmpV alone is
// L3-resident — R20 lesson: merging U+V made both tables contend)
__global__ __launch_bounds__(256) void agg_u_k(
    const int* __restrict__ rowPtrU, const ull* __restrict__ eU,
    const ushort* __restrict__ tmpV, ushort* __restrict__ Xu)
{
    const int lane = threadIdx.x & 63;
    const int n = blockIdx.x * 4 + (threadIdx.x >> 6);
    const uint lane4 = (uint)(((lane < 50) ? lane : 49) << 2);
    float a0[KSUP], a1[KSUP];
    agg_do<0, KSUP, 4, NU>(rowPtrU, eU, (const char*)tmpV, n, lane4, a0, a1);
    agg_store(Xu + (size_t)n * XW, lane, a0, a1);
}

// V-direction: gathers tmpU (LDS-free)
__global__ __launch_bounds__(256) void agg_v_k(
    const int* __restrict__ rowPtrV, const ull* __restrict__ eV,
    const ushort* __restrict__ tmpU, ushort* __restrict__ Xv)
{
    const int lane = threadIdx.x & 63;
    const int n = blockIdx.x * 4 + (threadIdx.x >> 6);
    const uint lane4 = (uint)(((lane < 50) ? lane : 49) << 2);
    float a0[KSUP], a1[KSUP];
    agg_do<0, 3, 8, NV>(rowPtrV, eV, (const char*)tmpU, n, lane4, a0, a1);
    agg_do<3, 2, 8, NV>(rowPtrV, eV, (const char*)tmpU, n, lane4, a0, a1);
    agg_store(Xv + (size_t)n * XW, lane, a0, a1);
}

// ---------------------------------------------------------------------------
// final decoder: int2 gathers; basis[b] = dot(embU[u], Vb[v][b]); out=basis@cls
__global__ __launch_bounds__(256) void dec_k(
    const int* __restrict__ ue, const int* __restrict__ ie,
    const ushort* __restrict__ embU, const ushort* __restrict__ Vb,
    const float* __restrict__ cls, float* __restrict__ out, int nE)
{
    int e = blockIdx.x * 8 + (threadIdx.x >> 5);
    if (e >= nE) return;
    int lane = threadIdx.x & 31;
    int u = ue[e], v = ie[e];
    const int2* pu2 = (const int2*)(embU + (size_t)u * DENC);        // 32 int2
    const int2* pv2 = (const int2*)(Vb + (size_t)v * (NBAS * DENC)); // 96 int2
    int2 uu = pu2[lane];                 // cols 4l..4l+3
    int2 bb[NBAS];
    #pragma unroll
    for (int b = 0; b < NBAS; ++b) bb[b] = pv2[b * 32 + lane];
    float uxl = lof((uint)uu.x), uxh = hif((uint)uu.x);
    float uyl = lof((uint)uu.y), uyh = hif((uint)uu.y);
    float s[NBAS];
    #pragma unroll
    for (int b = 0; b < NBAS; ++b) {
        float t = lof((uint)bb[b].x) * uxl;
        t = fmaf(hif((uint)bb[b].x), uxh, t);
        t = fmaf(lof((uint)bb[b].y), uyl, t);
        s[b] = fmaf(hif((uint)bb[b].y), uyh, t);
    }
    #pragma unroll
    for (int off = 16; off; off >>= 1)
        #pragma unroll
        for (int b = 0; b < NBAS; ++b) s[b] += __shfl_xor(s[b], off, 32);
    if (lane < NCLS) {
        float o = 0.f;
        #pragma unroll
        for (int b = 0; b < NBAS; ++b) o += s[b] * cls[b * NCLS + lane];
        out[(size_t)e * NCLS + lane] = o;
    }
}

// ---------------------------------------------------------------------------
extern "C" void kernel_launch(void* const* d_in, const int* in_sizes, int n_in,
                              void* d_out, int out_size, void* d_ws, size_t ws_size,
                              hipStream_t stream) {
    const int*   sup_u  = (const int*)  d_in[0];
    const int*   sup_i  = (const int*)  d_in[1];
    const float* sup_v  = (const float*)d_in[2];
    const float* u_in   = (const float*)d_in[3];
    const float* v_in   = (const float*)d_in[4];
    const float* u_side = (const float*)d_in[5];
    const float* v_side = (const float*)d_in[6];
    const int*   ue     = (const int*)  d_in[7];
    const int*   ie     = (const int*)  d_in[8];
    const float* W_enc  = (const float*)d_in[9];
    const float* Wu1    = (const float*)d_in[10];
    const float* bu1    = (const float*)d_in[11];
    const float* Wi1    = (const float*)d_in[12];
    const float* bi1    = (const float*)d_in[13];
    const float* Wu2    = (const float*)d_in[14];
    const float* Wi2    = (const float*)d_in[15];
    const float* dec_W  = (const float*)d_in[16];
    const float* deccls = (const float*)d_in[17];

    char* ws = (char*)d_ws;
    // timeline overlays: u_bf/v_bf live ph1-2 (enc GEMM); Xu/Xv (same size)
    // written by agg in ph3 after u_bf is dead.
    ushort* u_bf   = (ushort*)(ws);                     // [NU][512] 102.4M
    ushort* v_bf   = (ushort*)(ws + 102400000LL);       // [NV][512] 51.2M
    ushort* Xu     = (ushort*)(ws);                     // [NU][512] 102.4M
    ushort* Xv     = (ushort*)(ws + 102400000LL);       // [NV][512] 51.2M
    // CSR @176M (dead after agg); rowPtr regions padded for the +1 sentinel.
    int*    rowPtrU= (int*)(ws + 179000000LL);          // 2M + 4 sentinel
    int*    rowPtrV= (int*)(ws + 181200000LL);          // 1M + 4 sentinel
    int*    bCnt   = (int*)(ws + 185810000LL);          // [1470] contiguous
    ull*    eU     = (ull*)(ws + 186000000LL);          // [2M] 16M
    ull*    eV     = (ull*)(ws + 202000000LL);          // [2M] 16M ends 218M
    // tmp @220M (dead after agg): tmpU [NU][512] 102.4M, tmpV [NV][512] 51.2M
    ushort* tmpU   = (ushort*)(ws + 220000000LL);
    ushort* tmpV   = (ushort*)(ws + 323000000LL);       // ends 374.2M
    // L1 buckets: overlay on tmp region (dead before encoder GEMMs write tmp)
    ull*    bktU   = (ull*)(ws + 220000000LL);          // 980*2560*8  = 20.1M
    ull*    bktV   = (ull*)(ws + 241000000LL);          // 490*5120*8  = 20.1M
    // post-agg overlays:
    ushort* embUbf = (ushort*)(ws + 176000000LL);       // [NU][128] 25.6M (over CSR)
    ushort* embVbf = (ushort*)(ws + 202000000LL);       // [NV][128] 12.8M (over eV)
    ushort* Vb     = (ushort*)(ws + 220000000LL);       // [NV][384] 38.4M (over tmp)
    // weights @412M:
    ushort* WencT2 = (ushort*)(ws + 412000000LL);       // [512][512] 0.52M
    ushort* W2ufT  = (ushort*)(ws + 413000000LL);       // [128][576] 0.15M
    ushort* W2ifT  = (ushort*)(ws + 413200000LL);       // [128][576] 0.15M
    ushort* decbf  = (ushort*)(ws + 413400000LL);       // [384][128] 0.10M
    // side buffers @413.6M (written in prep, read in d2 — own region):
    ushort* sideU  = (ushort*)(ws + 413600000LL);       // [NU][64] 12.8M
    ushort* sideV  = (ushort*)(ws + 426400000LL);       // [NV][64] 6.4M ends 432.8M

    dim3 blk(256);

    // ---- phase 1: fused prep (binhist ∥ side dense ∥ weight cvts ∥ cvt_in) ----
    hipMemsetAsync(bCnt, 0, 8192, stream);              // bucket counters
    prep_k<<<dim3(PTOT), blk, 0, stream>>>(
        sup_u, sup_i, sup_v, bCnt, bktU, bktV,
        W_enc, WencT2, Wu2, Wi2, W2ufT, W2ifT, dec_W, decbf,
        u_in, v_in, u_bf, v_bf,
        u_side, v_side, Wu1, bu1, Wi1, bi1, sideU, sideV);
    scat3_k<<<dim3(NBT), blk, 0, stream>>>(bCnt, bktU, bktV,
                                           rowPtrU, rowPtrV, eU, eV);

    // ---- phase 2: fused encoder GEMMs (bf16 A; N=512 packed, 4 col tiles) ----
    gemm_enc_k<<<dim3(TMPW / 128, GU128 + GV128), blk, 0, stream>>>(
        u_bf, v_bf, WencT2, tmpU, tmpV);

    // ---- phase 3: CSR aggregation, U then V (separate launches: each
    //      gather table L3-resident alone) ----
    agg_u_k<<<dim3(NU / 4), blk, 0, stream>>>(rowPtrU, eU, tmpV, Xu);
    agg_v_k<<<dim3(NV / 4), blk, 0, stream>>>(rowPtrV, eV, tmpU, Xv);

    // ---- phase 4: fused dense2 (split A: X + sideBuf) -> emb bf16 ----
    gemm_d2_k<<<dim3(1, GU128 + GV128), blk, 0, stream>>>(
        Xu, Xv, sideU, sideV, W2ufT, W2ifT, embUbf, embVbf);

    // ---- phase 5: decoder precompute on V side: Vb = embV @ decbf^T ----
    gemm_bf16_k<<<dim3(3, GV128), blk, 0, stream>>>(embVbf, decbf, Vb, NV, 384, 128, 384);

    // ---- phase 6: final decoder over edges ----
    dec_k<<<dim3(NE / 8), blk, 0, stream>>>(ue, ie, embUbf, Vb, deccls, (float*)d_out, NE);
}